// Round 1
// baseline (1494.419 us; speedup 1.0000x reference)
//
#include <hip/hip_runtime.h>
#include <hip/hip_bf16.h>

#define NTOK 8192
#define DM 1024
#define NE 8
#define DH 2048
#define CAP 17408   // 16384 + 8*128 padding, multiple of 128
#define NRT 136     // CAP/128

typedef __attribute__((ext_vector_type(8))) short short8;
typedef __attribute__((ext_vector_type(4))) float float4v;

// ---------------- conversion kernels ----------------

__global__ __launch_bounds__(256) void k_xconvert(const float* __restrict__ x,
                                                  __hip_bfloat16* __restrict__ xb) {
    int i = blockIdx.x * 256 + threadIdx.x;  // float4 index
    const float4* x4 = (const float4*)x;
    float4 v = x4[i];
    __hip_bfloat16* d = xb + (size_t)i * 4;
    d[0] = __float2bfloat16(v.x);
    d[1] = __float2bfloat16(v.y);
    d[2] = __float2bfloat16(v.z);
    d[3] = __float2bfloat16(v.w);
}

// src: [z][R][C] fp32  ->  dst: [z][C][R] bf16
__global__ __launch_bounds__(256) void k_transpose(const float* __restrict__ src,
                                                   __hip_bfloat16* __restrict__ dst,
                                                   int R, int C) {
    __shared__ float t[32][33];
    size_t mat = (size_t)blockIdx.z * R * C;
    src += mat;
    dst += mat;
    int c0 = blockIdx.x * 32, r0 = blockIdx.y * 32;
    int tx = threadIdx.x & 31, ty = threadIdx.x >> 5;  // 32 x 8
#pragma unroll
    for (int i = 0; i < 4; i++) {
        int r = ty + i * 8;
        t[r][tx] = src[(size_t)(r0 + r) * C + c0 + tx];
    }
    __syncthreads();
#pragma unroll
    for (int i = 0; i < 4; i++) {
        int c = ty + i * 8;
        dst[(size_t)(c0 + c) * R + r0 + tx] = __float2bfloat16(t[tx][c]);
    }
}

// ---------------- router ----------------

__global__ __launch_bounds__(64) void k_router(const float* __restrict__ x,
                                               const float* __restrict__ rw,
                                               const float* __restrict__ rb,
                                               int* __restrict__ topidx,
                                               float* __restrict__ topw,
                                               int* __restrict__ cnt,
                                               float* __restrict__ sump,
                                               float* __restrict__ szent) {
    int n = blockIdx.x;
    int lane = threadIdx.x;
    const float* xr = x + (size_t)n * DM;
    float p[8] = {0.f, 0.f, 0.f, 0.f, 0.f, 0.f, 0.f, 0.f};
#pragma unroll
    for (int i = 0; i < 16; i++) {
        int d = lane + i * 64;
        float xv = xr[d];
        const float4* w4 = (const float4*)(rw + (size_t)d * 8);
        float4 wa = w4[0], wb = w4[1];
        p[0] += xv * wa.x; p[1] += xv * wa.y; p[2] += xv * wa.z; p[3] += xv * wa.w;
        p[4] += xv * wb.x; p[5] += xv * wb.y; p[6] += xv * wb.z; p[7] += xv * wb.w;
    }
#pragma unroll
    for (int e = 0; e < 8; e++) {
#pragma unroll
        for (int off = 32; off > 0; off >>= 1) p[e] += __shfl_down(p[e], off);
    }
    if (lane == 0) {
        float logits[8], probs[8];
        float mx = -1e30f;
#pragma unroll
        for (int e = 0; e < 8; e++) {
            logits[e] = p[e] + rb[e];
            mx = fmaxf(mx, logits[e]);
        }
        float se = 0.f;
#pragma unroll
        for (int e = 0; e < 8; e++) {
            probs[e] = __expf(logits[e] - mx);
            se += probs[e];
        }
        float inv = 1.f / se;
        float z = mx + logf(se);
        float ent = 0.f;
#pragma unroll
        for (int e = 0; e < 8; e++) {
            probs[e] *= inv;
            ent -= probs[e] * logf(probs[e] + 1e-10f);
        }
        // top-2, ties -> lowest index (strict >)
        int i0 = 0;
#pragma unroll
        for (int e = 1; e < 8; e++)
            if (probs[e] > probs[i0]) i0 = e;
        int i1 = (i0 == 0) ? 1 : 0;
#pragma unroll
        for (int e = 0; e < 8; e++)
            if (e != i0 && e != i1 && probs[e] > probs[i1]) i1 = e;
        // make sure i1 is the best non-i0 with lowest-index tie rule:
        // (loop above keeps first occurrence for ties since strict >)
        float w0 = probs[i0], w1v = probs[i1];
        float s = w0 + w1v + 1e-9f;
        w0 /= s;
        w1v /= s;
        topidx[2 * n] = i0;
        topidx[2 * n + 1] = i1;
        topw[2 * n] = w0;
        topw[2 * n + 1] = w1v;
        atomicAdd(&cnt[i0], 1);
        atomicAdd(&cnt[i1], 1);
#pragma unroll
        for (int e = 0; e < 8; e++) atomicAdd(&sump[e], probs[e]);
        atomicAdd(&szent[0], z * z);
        atomicAdd(&szent[1], ent);
    }
}

// ---------------- scan + scatter ----------------

__global__ void k_scan(const int* __restrict__ cnt, int* __restrict__ offs) {
    if (threadIdx.x == 0 && blockIdx.x == 0) {
        int o = 0;
        for (int e = 0; e < NE; e++) {
            offs[e] = o;
            o += (cnt[e] + 127) & ~127;
        }
        offs[NE] = o;
    }
}

__global__ __launch_bounds__(256) void k_scatter(const int* __restrict__ topidx,
                                                 const float* __restrict__ topw,
                                                 const int* __restrict__ offs,
                                                 int* __restrict__ cnt2,
                                                 int* __restrict__ rowtok,
                                                 float* __restrict__ roww,
                                                 int* __restrict__ slot) {
    int n = blockIdx.x * 256 + threadIdx.x;
    if (n >= NTOK) return;
#pragma unroll
    for (int k = 0; k < 2; k++) {
        int e = topidx[2 * n + k];
        int pos = atomicAdd(&cnt2[e], 1);
        int row = offs[e] + pos;
        rowtok[row] = n;
        roww[row] = topw[2 * n + k];
        slot[2 * n + k] = row;
    }
}

// ---------------- GEMM1: hidden = gelu(x_gathered @ w1 + b1), bf16 out ----------------
// LDS fragment layout: [kg][m][8] shorts, element (m, kg*8+j) at (kg*128+m)*8+j

__global__ __launch_bounds__(256) void k_gemm1(const __hip_bfloat16* __restrict__ xb,
                                               const __hip_bfloat16* __restrict__ w1T,  // [E][H][D]
                                               const float* __restrict__ b1,            // [E][H]
                                               const int* __restrict__ rowtok,
                                               const int* __restrict__ offs,
                                               __hip_bfloat16* __restrict__ hid) {      // [CAP][DH]
    int row0 = blockIdx.y * 128;
    if (row0 >= offs[NE]) return;
    int e = 0;
    while (row0 >= offs[e + 1]) e++;
    int h0 = blockIdx.x * 128;
    int tid = threadIdx.x;

    __shared__ __align__(16) short A_lds[4096];
    __shared__ __align__(16) short B_lds[4096];
    __shared__ int tokoff[128];
    if (tid < 128) {
        int t = rowtok[row0 + tid];
        tokoff[tid] = (t < 0) ? -1 : t * DM;
    }
    __syncthreads();

    int m = tid & 127, kg = tid >> 7;  // kg in {0,1}; slots (kg,m) and (kg+2,m)
    int tb = tokoff[m];
    bool aval = tb >= 0;
    const short* asrc = (const short*)xb + (aval ? tb : 0) + kg * 8;
    const short* bsrc = (const short*)w1T + ((size_t)e * DH + h0 + m) * DM + kg * 8;
    short* awr0 = &A_lds[(kg * 128 + m) * 8];
    short* awr1 = &A_lds[((kg + 2) * 128 + m) * 8];
    short* bwr0 = &B_lds[(kg * 128 + m) * 8];
    short* bwr1 = &B_lds[((kg + 2) * 128 + m) * 8];

    int lane = tid & 63, wv = tid >> 6;
    int wm = (wv >> 1) * 64, wn = (wv & 1) * 64;
    int quad = lane >> 4, l16 = lane & 15;
    int a_off[4], b_off[4];
#pragma unroll
    for (int t = 0; t < 4; t++) {
        a_off[t] = (quad * 128 + wm + t * 16 + l16) * 8;
        b_off[t] = (quad * 128 + wn + t * 16 + l16) * 8;
    }
    float4v acc[4][4];
#pragma unroll
    for (int i = 0; i < 4; i++)
#pragma unroll
        for (int j = 0; j < 4; j++) {
            float4v z = {0.f, 0.f, 0.f, 0.f};
            acc[i][j] = z;
        }

    for (int k0 = 0; k0 < DM; k0 += 32) {
        int4 av0 = {0, 0, 0, 0}, av1 = {0, 0, 0, 0};
        if (aval) {
            av0 = *(const int4*)(asrc + k0);
            av1 = *(const int4*)(asrc + k0 + 16);
        }
        int4 bv0 = *(const int4*)(bsrc + k0);
        int4 bv1 = *(const int4*)(bsrc + k0 + 16);
        __syncthreads();  // previous iter's ds_reads done before overwrite
        *(int4*)awr0 = av0;
        *(int4*)awr1 = av1;
        *(int4*)bwr0 = bv0;
        *(int4*)bwr1 = bv1;
        __syncthreads();
#pragma unroll
        for (int mt = 0; mt < 4; mt++) {
            short8 a = *(const short8*)&A_lds[a_off[mt]];
#pragma unroll
            for (int nt = 0; nt < 4; nt++) {
                short8 b = *(const short8*)&B_lds[b_off[nt]];
                acc[mt][nt] = __builtin_amdgcn_mfma_f32_16x16x32_bf16(a, b, acc[mt][nt], 0, 0, 0);
            }
        }
    }

    const float* b1e = b1 + (size_t)e * DH + h0;
#pragma unroll
    for (int mt = 0; mt < 4; mt++) {
#pragma unroll
        for (int nt = 0; nt < 4; nt++) {
            int rl = wm + mt * 16 + quad * 4;
            int cl = wn + nt * 16 + l16;
            float bias = b1e[cl];
#pragma unroll
            for (int r = 0; r < 4; r++) {
                float v = acc[mt][nt][r] + bias;
                v = 0.5f * v * (1.0f + erff(v * 0.70710678118654752f));  // exact gelu
                hid[(size_t)(row0 + rl + r) * DH + h0 + cl] = __float2bfloat16(v);
            }
        }
    }
}

// ---------------- GEMM2: outb = (hidden @ w2 + b2) * weight, fp32 out ----------------

__global__ __launch_bounds__(256) void k_gemm2(const __hip_bfloat16* __restrict__ hid,  // [CAP][DH]
                                               const __hip_bfloat16* __restrict__ w2T,  // [E][D][H]
                                               const float* __restrict__ b2,            // [E][D]
                                               const float* __restrict__ roww,
                                               const int* __restrict__ offs,
                                               float* __restrict__ outb) {              // [CAP][DM]
    int row0 = blockIdx.y * 128;
    if (row0 >= offs[NE]) return;
    int e = 0;
    while (row0 >= offs[e + 1]) e++;
    int d0 = blockIdx.x * 128;
    int tid = threadIdx.x;

    __shared__ __align__(16) short A_lds[4096];
    __shared__ __align__(16) short B_lds[4096];

    int m = tid & 127, kg = tid >> 7;
    const short* asrc = (const short*)hid + (size_t)(row0 + m) * DH + kg * 8;
    const short* bsrc = (const short*)w2T + ((size_t)e * DM + d0 + m) * DH + kg * 8;
    short* awr0 = &A_lds[(kg * 128 + m) * 8];
    short* awr1 = &A_lds[((kg + 2) * 128 + m) * 8];
    short* bwr0 = &B_lds[(kg * 128 + m) * 8];
    short* bwr1 = &B_lds[((kg + 2) * 128 + m) * 8];

    int lane = tid & 63, wv = tid >> 6;
    int wm = (wv >> 1) * 64, wn = (wv & 1) * 64;
    int quad = lane >> 4, l16 = lane & 15;
    int a_off[4], b_off[4];
#pragma unroll
    for (int t = 0; t < 4; t++) {
        a_off[t] = (quad * 128 + wm + t * 16 + l16) * 8;
        b_off[t] = (quad * 128 + wn + t * 16 + l16) * 8;
    }
    float4v acc[4][4];
#pragma unroll
    for (int i = 0; i < 4; i++)
#pragma unroll
        for (int j = 0; j < 4; j++) {
            float4v z = {0.f, 0.f, 0.f, 0.f};
            acc[i][j] = z;
        }

    for (int k0 = 0; k0 < DH; k0 += 32) {
        int4 av0 = *(const int4*)(asrc + k0);
        int4 av1 = *(const int4*)(asrc + k0 + 16);
        int4 bv0 = *(const int4*)(bsrc + k0);
        int4 bv1 = *(const int4*)(bsrc + k0 + 16);
        __syncthreads();
        *(int4*)awr0 = av0;
        *(int4*)awr1 = av1;
        *(int4*)bwr0 = bv0;
        *(int4*)bwr1 = bv1;
        __syncthreads();
#pragma unroll
        for (int mt = 0; mt < 4; mt++) {
            short8 a = *(const short8*)&A_lds[a_off[mt]];
#pragma unroll
            for (int nt = 0; nt < 4; nt++) {
                short8 b = *(const short8*)&B_lds[b_off[nt]];
                acc[mt][nt] = __builtin_amdgcn_mfma_f32_16x16x32_bf16(a, b, acc[mt][nt], 0, 0, 0);
            }
        }
    }

    const float* b2e = b2 + (size_t)e * DM + d0;
#pragma unroll
    for (int mt = 0; mt < 4; mt++) {
#pragma unroll
        for (int nt = 0; nt < 4; nt++) {
            int rl = wm + mt * 16 + quad * 4;
            int cl = wn + nt * 16 + l16;
            float bias = b2e[cl];
#pragma unroll
            for (int r = 0; r < 4; r++) {
                int grow = row0 + rl + r;
                float v = (acc[mt][nt][r] + bias) * roww[grow];
                outb[(size_t)grow * DM + d0 + cl] = v;
            }
        }
    }
}

// ---------------- combine + finalize ----------------

__global__ __launch_bounds__(256) void k_combine(const float* __restrict__ outb,
                                                 const int* __restrict__ slot,
                                                 float* __restrict__ y) {
    int n = blockIdx.x;
    int r0 = slot[2 * n], r1 = slot[2 * n + 1];
    const float4* p0 = (const float4*)(outb + (size_t)r0 * DM);
    const float4* p1 = (const float4*)(outb + (size_t)r1 * DM);
    float4 a = p0[threadIdx.x], b = p1[threadIdx.x];
    float4 c;
    c.x = a.x + b.x;
    c.y = a.y + b.y;
    c.z = a.z + b.z;
    c.w = a.w + b.w;
    ((float4*)(y + (size_t)n * DM))[threadIdx.x] = c;
}

__global__ void k_finalize(const int* __restrict__ cnt, const float* __restrict__ sump,
                           const float* __restrict__ szent, float* __restrict__ out) {
    if (threadIdx.x == 0 && blockIdx.x == 0) {
        const float invN = 1.0f / (float)NTOK;
        float lb = 0.f;
        float f[NE], P[NE];
        for (int e = 0; e < NE; e++) {
            f[e] = (float)cnt[e] * invN;
            P[e] = sump[e] * invN;
            lb += f[e] * P[e];
        }
        size_t base = (size_t)NTOK * DM;
        out[base + 0] = -(float)NE * lb;      // lb_loss
        out[base + 1] = szent[0] * invN;      // z_loss
        out[base + 2] = szent[1] * invN;      // entropy
        for (int e = 0; e < NE; e++) out[base + 3 + e] = f[e];
        for (int e = 0; e < NE; e++) out[base + 11 + e] = P[e];
    }
}

// ---------------- launch ----------------

extern "C" void kernel_launch(void* const* d_in, const int* in_sizes, int n_in,
                              void* d_out, int out_size, void* d_ws, size_t ws_size,
                              hipStream_t stream) {
    const float* x  = (const float*)d_in[0];
    const float* rw = (const float*)d_in[1];
    const float* rb = (const float*)d_in[2];
    const float* w1 = (const float*)d_in[3];
    const float* b1 = (const float*)d_in[4];
    const float* w2 = (const float*)d_in[5];
    const float* b2 = (const float*)d_in[6];
    float* out = (float*)d_out;

    char* ws = (char*)d_ws;
    size_t o = 0;
    auto alloc = [&](size_t bytes) {
        size_t r = o;
        o = (o + bytes + 255) & ~(size_t)255;
        return r;
    };
    __hip_bfloat16* w1T = (__hip_bfloat16*)(ws + alloc((size_t)NE * DM * DH * 2));
    __hip_bfloat16* w2T = (__hip_bfloat16*)(ws + alloc((size_t)NE * DM * DH * 2));
    __hip_bfloat16* xb  = (__hip_bfloat16*)(ws + alloc((size_t)NTOK * DM * 2));
    __hip_bfloat16* hid = (__hip_bfloat16*)(ws + alloc((size_t)CAP * DH * 2));
    float* outb = (float*)(ws + alloc((size_t)CAP * DM * 4));
    int* rowtok = (int*)(ws + alloc(CAP * 4));
    size_t zstart = o;
    float* roww  = (float*)(ws + alloc(CAP * 4));
    int* cnt     = (int*)(ws + alloc(64));
    int* cnt2    = (int*)(ws + alloc(64));
    int* offs    = (int*)(ws + alloc(64));
    float* sump  = (float*)(ws + alloc(64));
    float* szent = (float*)(ws + alloc(64));
    size_t zend = o;
    int* topidx = (int*)(ws + alloc((size_t)NTOK * 2 * 4));
    float* topw = (float*)(ws + alloc((size_t)NTOK * 2 * 4));
    int* slot   = (int*)(ws + alloc((size_t)NTOK * 2 * 4));

    hipMemsetAsync(rowtok, 0xFF, (size_t)CAP * 4, stream);          // pad rows -> token -1
    hipMemsetAsync(ws + zstart, 0, zend - zstart, stream);          // weights/counters/stats

    k_xconvert<<<NTOK * DM / 1024, 256, 0, stream>>>(x, xb);
    k_transpose<<<dim3(DH / 32, DM / 32, NE), 256, 0, stream>>>(w1, w1T, DM, DH);  // -> [E][H][D]
    k_transpose<<<dim3(DM / 32, DH / 32, NE), 256, 0, stream>>>(w2, w2T, DH, DM);  // -> [E][D][H]
    k_router<<<NTOK, 64, 0, stream>>>(x, rw, rb, topidx, topw, cnt, sump, szent);
    k_scan<<<1, 1, 0, stream>>>(cnt, offs);
    k_scatter<<<NTOK / 256, 256, 0, stream>>>(topidx, topw, offs, cnt2, rowtok, roww, slot);
    k_gemm1<<<dim3(DH / 128, NRT), 256, 0, stream>>>(xb, w1T, b1, rowtok, offs, hid);
    k_gemm2<<<dim3(DM / 128, NRT), 256, 0, stream>>>(hid, w2T, b2, roww, offs, outb);
    k_combine<<<NTOK, 256, 0, stream>>>(outb, slot, out);
    k_finalize<<<1, 1, 0, stream>>>(cnt, sump, szent, out);
}

// Round 2
// 604.126 us; speedup vs baseline: 2.4737x; 2.4737x over previous
//
#include <hip/hip_runtime.h>
#include <hip/hip_bf16.h>

#define NTOK 8192
#define DM 1024
#define NE 8
#define DH 2048
#define CAP 17408   // 16384 + 8*128 padding, multiple of 128
#define NRT 136     // CAP/128

typedef __attribute__((ext_vector_type(8))) short short8;
typedef __attribute__((ext_vector_type(4))) float float4v;

// async global->LDS DMA, 16B per lane; LDS dest must be wave-uniform base + lane*16
#define ASYNC_COPY16(gsrc, ldst)                                                              \
    __builtin_amdgcn_global_load_lds((const __attribute__((address_space(1))) unsigned int*)(gsrc), \
                                     (__attribute__((address_space(3))) unsigned int*)(ldst), \
                                     16, 0, 0)

// ---------------- conversion kernels ----------------

__global__ __launch_bounds__(256) void k_xconvert(const float* __restrict__ x,
                                                  __hip_bfloat16* __restrict__ xb) {
    int i = blockIdx.x * 256 + threadIdx.x;  // float4 index
    const float4* x4 = (const float4*)x;
    float4 v = x4[i];
    __hip_bfloat16* d = xb + (size_t)i * 4;
    d[0] = __float2bfloat16(v.x);
    d[1] = __float2bfloat16(v.y);
    d[2] = __float2bfloat16(v.z);
    d[3] = __float2bfloat16(v.w);
}

// src: [z][R][C] fp32  ->  dst: [z][C][R] bf16
__global__ __launch_bounds__(256) void k_transpose(const float* __restrict__ src,
                                                   __hip_bfloat16* __restrict__ dst,
                                                   int R, int C) {
    __shared__ float t[32][33];
    size_t mat = (size_t)blockIdx.z * R * C;
    src += mat;
    dst += mat;
    int c0 = blockIdx.x * 32, r0 = blockIdx.y * 32;
    int tx = threadIdx.x & 31, ty = threadIdx.x >> 5;  // 32 x 8
#pragma unroll
    for (int i = 0; i < 4; i++) {
        int r = ty + i * 8;
        t[r][tx] = src[(size_t)(r0 + r) * C + c0 + tx];
    }
    __syncthreads();
#pragma unroll
    for (int i = 0; i < 4; i++) {
        int c = ty + i * 8;
        dst[(size_t)(c0 + c) * R + r0 + tx] = __float2bfloat16(t[tx][c]);
    }
}

// ---------------- router (atomic-free) ----------------
// wave per token; per-token numerics identical to the passing round.

__global__ __launch_bounds__(256) void k_router(const float* __restrict__ x,
                                                const float* __restrict__ rw,
                                                const float* __restrict__ rb,
                                                int* __restrict__ topidx,
                                                float* __restrict__ topw,
                                                float* __restrict__ probs8,   // [NTOK][8]
                                                float* __restrict__ zent) {   // [NTOK][2] = z^2, ent
    int lane = threadIdx.x & 63, wv = threadIdx.x >> 6;
    int n = blockIdx.x * 4 + wv;
    const float* xr = x + (size_t)n * DM;
    float p[8] = {0.f, 0.f, 0.f, 0.f, 0.f, 0.f, 0.f, 0.f};
#pragma unroll
    for (int i = 0; i < 16; i++) {
        int d = lane + i * 64;
        float xv = xr[d];
        const float4* w4 = (const float4*)(rw + (size_t)d * 8);
        float4 wa = w4[0], wb = w4[1];
        p[0] += xv * wa.x; p[1] += xv * wa.y; p[2] += xv * wa.z; p[3] += xv * wa.w;
        p[4] += xv * wb.x; p[5] += xv * wb.y; p[6] += xv * wb.z; p[7] += xv * wb.w;
    }
#pragma unroll
    for (int e = 0; e < 8; e++) {
#pragma unroll
        for (int off = 32; off > 0; off >>= 1) p[e] += __shfl_down(p[e], off);
    }
    if (lane == 0) {
        float logits[8], probs[8];
        float mx = -1e30f;
#pragma unroll
        for (int e = 0; e < 8; e++) {
            logits[e] = p[e] + rb[e];
            mx = fmaxf(mx, logits[e]);
        }
        float se = 0.f;
#pragma unroll
        for (int e = 0; e < 8; e++) {
            probs[e] = __expf(logits[e] - mx);
            se += probs[e];
        }
        float inv = 1.f / se;
        float z = mx + logf(se);
        float ent = 0.f;
#pragma unroll
        for (int e = 0; e < 8; e++) {
            probs[e] *= inv;
            ent -= probs[e] * logf(probs[e] + 1e-10f);
        }
        // top-2, ties -> lowest index (strict >)
        int i0 = 0;
#pragma unroll
        for (int e = 1; e < 8; e++)
            if (probs[e] > probs[i0]) i0 = e;
        int i1 = (i0 == 0) ? 1 : 0;
#pragma unroll
        for (int e = 0; e < 8; e++)
            if (e != i0 && e != i1 && probs[e] > probs[i1]) i1 = e;
        float w0 = probs[i0], w1v = probs[i1];
        float s = w0 + w1v + 1e-9f;
        topidx[2 * n] = i0;
        topidx[2 * n + 1] = i1;
        topw[2 * n] = w0 / s;
        topw[2 * n + 1] = w1v / s;
        float* pr = probs8 + (size_t)n * 8;
#pragma unroll
        for (int e = 0; e < 8; e++) pr[e] = probs[e];
        zent[2 * n] = z * z;
        zent[2 * n + 1] = ent;
    }
}

// ---------------- stats reduction (32 blocks -> 576 atomics total) ----------------

__global__ __launch_bounds__(256) void k_stats(const int* __restrict__ topidx,
                                               const float* __restrict__ probs8,
                                               const float* __restrict__ zent,
                                               float* __restrict__ fcnt,   // [8]
                                               float* __restrict__ sump,   // [8]
                                               float* __restrict__ szent) {// [2]
    int n = blockIdx.x * 256 + threadIdx.x;  // grid covers NTOK exactly
    float v[18];
    int e0 = topidx[2 * n], e1 = topidx[2 * n + 1];
#pragma unroll
    for (int e = 0; e < 8; e++) v[e] = (float)((e == e0) + (e == e1));
    const float4* p4 = (const float4*)(probs8 + (size_t)n * 8);
    float4 pa = p4[0], pb = p4[1];
    v[8] = pa.x; v[9] = pa.y; v[10] = pa.z; v[11] = pa.w;
    v[12] = pb.x; v[13] = pb.y; v[14] = pb.z; v[15] = pb.w;
    v[16] = zent[2 * n];
    v[17] = zent[2 * n + 1];
#pragma unroll
    for (int i = 0; i < 18; i++)
#pragma unroll
        for (int off = 32; off > 0; off >>= 1) v[i] += __shfl_down(v[i], off);
    __shared__ float part[4][18];
    int lane = threadIdx.x & 63, wv = threadIdx.x >> 6;
    if (lane == 0)
#pragma unroll
        for (int i = 0; i < 18; i++) part[wv][i] = v[i];
    __syncthreads();
    if (threadIdx.x == 0) {
#pragma unroll
        for (int i = 0; i < 18; i++) {
            float s = part[0][i] + part[1][i] + part[2][i] + part[3][i];
            if (i < 8) atomicAdd(&fcnt[i], s);
            else if (i < 16) atomicAdd(&sump[i - 8], s);
            else atomicAdd(&szent[i - 16], s);
        }
    }
}

// ---------------- scan + scatter ----------------

__global__ void k_scan(const float* __restrict__ fcnt, int* __restrict__ offs) {
    if (threadIdx.x == 0 && blockIdx.x == 0) {
        int o = 0;
        for (int e = 0; e < NE; e++) {
            offs[e] = o;
            int c = (int)(fcnt[e] + 0.5f);
            o += (c + 127) & ~127;
        }
        offs[NE] = o;
    }
}

__global__ __launch_bounds__(256) void k_scatter(const int* __restrict__ topidx,
                                                 const float* __restrict__ topw,
                                                 const int* __restrict__ offs,
                                                 int* __restrict__ cnt2,
                                                 int* __restrict__ rowtok,
                                                 float* __restrict__ roww,
                                                 int* __restrict__ slot) {
    __shared__ int lcnt[8], lbase[8];
    int tid = threadIdx.x;
    if (tid < 8) lcnt[tid] = 0;
    __syncthreads();
    int n = blockIdx.x * 256 + tid;
    int e0 = topidx[2 * n], e1 = topidx[2 * n + 1];
    int p0 = atomicAdd(&lcnt[e0], 1);
    int p1 = atomicAdd(&lcnt[e1], 1);
    __syncthreads();
    if (tid < 8) lbase[tid] = atomicAdd(&cnt2[tid], lcnt[tid]);
    __syncthreads();
    int r0 = offs[e0] + lbase[e0] + p0;
    int r1 = offs[e1] + lbase[e1] + p1;
    rowtok[r0] = n; roww[r0] = topw[2 * n];     slot[2 * n] = r0;
    rowtok[r1] = n; roww[r1] = topw[2 * n + 1]; slot[2 * n + 1] = r1;
}

// ---------------- GEMM1: hidden = gelu(x_gathered @ w1 + b1), bf16 out ----------------
// LDS fragment layout: [kg][m][8] shorts; global_load_lds staging (wave-uniform base + lane*16)

__global__ __launch_bounds__(256) void k_gemm1(const __hip_bfloat16* __restrict__ xb,
                                               const __hip_bfloat16* __restrict__ w1T,  // [E][H][D]
                                               const float* __restrict__ b1,            // [E][H]
                                               const int* __restrict__ rowtok,
                                               const int* __restrict__ offs,
                                               __hip_bfloat16* __restrict__ hid) {      // [CAP][DH]
    int row0 = blockIdx.y * 128;
    if (row0 >= offs[NE]) return;
    int e = 0;
    while (row0 >= offs[e + 1]) e++;
    int h0 = blockIdx.x * 128;
    int tid = threadIdx.x;

    __shared__ __align__(16) short A_lds[4096];
    __shared__ __align__(16) short B_lds[4096];
    __shared__ int tokoff[128];
    if (tid < 128) {
        int t = rowtok[row0 + tid];
        tokoff[tid] = (t < 0 ? 0 : t) * DM;  // pad rows compute on token 0 (output unused)
    }
    __syncthreads();

    int m = tid & 127, kg = tid >> 7;  // kg in {0,1}; slots (kg,m) and (kg+2,m)
    const short* asrc = (const short*)xb + tokoff[m] + kg * 8;
    const short* bsrc = (const short*)w1T + ((size_t)e * DH + h0 + m) * DM + kg * 8;
    short* awr0 = &A_lds[(kg * 128 + m) * 8];
    short* awr1 = &A_lds[((kg + 2) * 128 + m) * 8];
    short* bwr0 = &B_lds[(kg * 128 + m) * 8];
    short* bwr1 = &B_lds[((kg + 2) * 128 + m) * 8];

    int lane = tid & 63, wv = tid >> 6;
    int wm = (wv >> 1) * 64, wn = (wv & 1) * 64;
    int quad = lane >> 4, l16 = lane & 15;
    int a_off[4], b_off[4];
#pragma unroll
    for (int t = 0; t < 4; t++) {
        a_off[t] = (quad * 128 + wm + t * 16 + l16) * 8;
        b_off[t] = (quad * 128 + wn + t * 16 + l16) * 8;
    }
    float4v acc[4][4];
#pragma unroll
    for (int i = 0; i < 4; i++)
#pragma unroll
        for (int j = 0; j < 4; j++) {
            float4v z = {0.f, 0.f, 0.f, 0.f};
            acc[i][j] = z;
        }

    for (int k0 = 0; k0 < DM; k0 += 32) {
        __syncthreads();  // prev iter's ds_reads done before overwrite
        ASYNC_COPY16(asrc + k0, awr0);
        ASYNC_COPY16(asrc + k0 + 16, awr1);
        ASYNC_COPY16(bsrc + k0, bwr0);
        ASYNC_COPY16(bsrc + k0 + 16, bwr1);
        __syncthreads();  // drains vmcnt -> LDS visible
#pragma unroll
        for (int mt = 0; mt < 4; mt++) {
            short8 a = *(const short8*)&A_lds[a_off[mt]];
#pragma unroll
            for (int nt = 0; nt < 4; nt++) {
                short8 b = *(const short8*)&B_lds[b_off[nt]];
                acc[mt][nt] = __builtin_amdgcn_mfma_f32_16x16x32_bf16(a, b, acc[mt][nt], 0, 0, 0);
            }
        }
    }

    const float* b1e = b1 + (size_t)e * DH + h0;
#pragma unroll
    for (int mt = 0; mt < 4; mt++) {
#pragma unroll
        for (int nt = 0; nt < 4; nt++) {
            int rl = wm + mt * 16 + quad * 4;
            int cl = wn + nt * 16 + l16;
            float bias = b1e[cl];
#pragma unroll
            for (int r = 0; r < 4; r++) {
                float v = acc[mt][nt][r] + bias;
                v = 0.5f * v * (1.0f + erff(v * 0.70710678118654752f));  // exact gelu
                hid[(size_t)(row0 + rl + r) * DH + h0 + cl] = __float2bfloat16(v);
            }
        }
    }
}

// ---------------- GEMM2: outb = (hidden @ w2 + b2) * weight, fp32 out ----------------

__global__ __launch_bounds__(256) void k_gemm2(const __hip_bfloat16* __restrict__ hid,  // [CAP][DH]
                                               const __hip_bfloat16* __restrict__ w2T,  // [E][D][H]
                                               const float* __restrict__ b2,            // [E][D]
                                               const float* __restrict__ roww,
                                               const int* __restrict__ offs,
                                               float* __restrict__ outb) {              // [CAP][DM]
    int row0 = blockIdx.y * 128;
    if (row0 >= offs[NE]) return;
    int e = 0;
    while (row0 >= offs[e + 1]) e++;
    int d0 = blockIdx.x * 128;
    int tid = threadIdx.x;

    __shared__ __align__(16) short A_lds[4096];
    __shared__ __align__(16) short B_lds[4096];

    int m = tid & 127, kg = tid >> 7;
    const short* asrc = (const short*)hid + (size_t)(row0 + m) * DH + kg * 8;
    const short* bsrc = (const short*)w2T + ((size_t)e * DM + d0 + m) * DH + kg * 8;
    short* awr0 = &A_lds[(kg * 128 + m) * 8];
    short* awr1 = &A_lds[((kg + 2) * 128 + m) * 8];
    short* bwr0 = &B_lds[(kg * 128 + m) * 8];
    short* bwr1 = &B_lds[((kg + 2) * 128 + m) * 8];

    int lane = tid & 63, wv = tid >> 6;
    int wm = (wv >> 1) * 64, wn = (wv & 1) * 64;
    int quad = lane >> 4, l16 = lane & 15;
    int a_off[4], b_off[4];
#pragma unroll
    for (int t = 0; t < 4; t++) {
        a_off[t] = (quad * 128 + wm + t * 16 + l16) * 8;
        b_off[t] = (quad * 128 + wn + t * 16 + l16) * 8;
    }
    float4v acc[4][4];
#pragma unroll
    for (int i = 0; i < 4; i++)
#pragma unroll
        for (int j = 0; j < 4; j++) {
            float4v z = {0.f, 0.f, 0.f, 0.f};
            acc[i][j] = z;
        }

    for (int k0 = 0; k0 < DH; k0 += 32) {
        __syncthreads();
        ASYNC_COPY16(asrc + k0, awr0);
        ASYNC_COPY16(asrc + k0 + 16, awr1);
        ASYNC_COPY16(bsrc + k0, bwr0);
        ASYNC_COPY16(bsrc + k0 + 16, bwr1);
        __syncthreads();
#pragma unroll
        for (int mt = 0; mt < 4; mt++) {
            short8 a = *(const short8*)&A_lds[a_off[mt]];
#pragma unroll
            for (int nt = 0; nt < 4; nt++) {
                short8 b = *(const short8*)&B_lds[b_off[nt]];
                acc[mt][nt] = __builtin_amdgcn_mfma_f32_16x16x32_bf16(a, b, acc[mt][nt], 0, 0, 0);
            }
        }
    }

    const float* b2e = b2 + (size_t)e * DM + d0;
#pragma unroll
    for (int mt = 0; mt < 4; mt++) {
#pragma unroll
        for (int nt = 0; nt < 4; nt++) {
            int rl = wm + mt * 16 + quad * 4;
            int cl = wn + nt * 16 + l16;
            float bias = b2e[cl];
#pragma unroll
            for (int r = 0; r < 4; r++) {
                int grow = row0 + rl + r;
                float v = (acc[mt][nt][r] + bias) * roww[grow];
                outb[(size_t)grow * DM + d0 + cl] = v;
            }
        }
    }
}

// ---------------- combine + finalize ----------------

__global__ __launch_bounds__(256) void k_combine(const float* __restrict__ outb,
                                                 const int* __restrict__ slot,
                                                 float* __restrict__ y) {
    int n = blockIdx.x;
    int r0 = slot[2 * n], r1 = slot[2 * n + 1];
    const float4* p0 = (const float4*)(outb + (size_t)r0 * DM);
    const float4* p1 = (const float4*)(outb + (size_t)r1 * DM);
    float4 a = p0[threadIdx.x], b = p1[threadIdx.x];
    float4 c;
    c.x = a.x + b.x;
    c.y = a.y + b.y;
    c.z = a.z + b.z;
    c.w = a.w + b.w;
    ((float4*)(y + (size_t)n * DM))[threadIdx.x] = c;
}

__global__ void k_finalize(const float* __restrict__ fcnt, const float* __restrict__ sump,
                           const float* __restrict__ szent, float* __restrict__ out) {
    if (threadIdx.x == 0 && blockIdx.x == 0) {
        const float invN = 1.0f / (float)NTOK;
        float lb = 0.f;
        float f[NE], P[NE];
        for (int e = 0; e < NE; e++) {
            f[e] = fcnt[e] * invN;
            P[e] = sump[e] * invN;
            lb += f[e] * P[e];
        }
        size_t base = (size_t)NTOK * DM;
        out[base + 0] = -(float)NE * lb;      // lb_loss
        out[base + 1] = szent[0] * invN;      // z_loss
        out[base + 2] = szent[1] * invN;      // entropy
        for (int e = 0; e < NE; e++) out[base + 3 + e] = f[e];
        for (int e = 0; e < NE; e++) out[base + 11 + e] = P[e];
    }
}

// ---------------- launch ----------------

extern "C" void kernel_launch(void* const* d_in, const int* in_sizes, int n_in,
                              void* d_out, int out_size, void* d_ws, size_t ws_size,
                              hipStream_t stream) {
    const float* x  = (const float*)d_in[0];
    const float* rw = (const float*)d_in[1];
    const float* rb = (const float*)d_in[2];
    const float* w1 = (const float*)d_in[3];
    const float* b1 = (const float*)d_in[4];
    const float* w2 = (const float*)d_in[5];
    const float* b2 = (const float*)d_in[6];
    float* out = (float*)d_out;

    char* ws = (char*)d_ws;
    size_t o = 0;
    auto alloc = [&](size_t bytes) {
        size_t r = o;
        o = (o + bytes + 255) & ~(size_t)255;
        return r;
    };
    __hip_bfloat16* w1T = (__hip_bfloat16*)(ws + alloc((size_t)NE * DM * DH * 2));
    __hip_bfloat16* w2T = (__hip_bfloat16*)(ws + alloc((size_t)NE * DM * DH * 2));
    __hip_bfloat16* xb  = (__hip_bfloat16*)(ws + alloc((size_t)NTOK * DM * 2));
    __hip_bfloat16* hid = (__hip_bfloat16*)(ws + alloc((size_t)CAP * DH * 2));
    float* outb = (float*)(ws + alloc((size_t)CAP * DM * 4));
    int* rowtok = (int*)(ws + alloc(CAP * 4));
    size_t zstart = o;
    float* roww  = (float*)(ws + alloc(CAP * 4));
    float* fcnt  = (float*)(ws + alloc(64));
    int* cnt2    = (int*)(ws + alloc(64));
    int* offs    = (int*)(ws + alloc(64));
    float* sump  = (float*)(ws + alloc(64));
    float* szent = (float*)(ws + alloc(64));
    size_t zend = o;
    int* topidx = (int*)(ws + alloc((size_t)NTOK * 2 * 4));
    float* topw = (float*)(ws + alloc((size_t)NTOK * 2 * 4));
    int* slot   = (int*)(ws + alloc((size_t)NTOK * 2 * 4));
    float* probs8 = (float*)(ws + alloc((size_t)NTOK * 8 * 4));
    float* zent   = (float*)(ws + alloc((size_t)NTOK * 2 * 4));

    hipMemsetAsync(rowtok, 0xFF, (size_t)CAP * 4, stream);   // pad rows -> token -1
    hipMemsetAsync(ws + zstart, 0, zend - zstart, stream);   // weights/counters/stats

    k_xconvert<<<NTOK * DM / 1024, 256, 0, stream>>>(x, xb);
    k_transpose<<<dim3(DH / 32, DM / 32, NE), 256, 0, stream>>>(w1, w1T, DM, DH);  // -> [E][H][D]
    k_transpose<<<dim3(DM / 32, DH / 32, NE), 256, 0, stream>>>(w2, w2T, DH, DM);  // -> [E][D][H]
    k_router<<<NTOK / 4, 256, 0, stream>>>(x, rw, rb, topidx, topw, probs8, zent);
    k_stats<<<NTOK / 256, 256, 0, stream>>>(topidx, probs8, zent, fcnt, sump, szent);
    k_scan<<<1, 1, 0, stream>>>(fcnt, offs);
    k_scatter<<<NTOK / 256, 256, 0, stream>>>(topidx, topw, offs, cnt2, rowtok, roww, slot);
    k_gemm1<<<dim3(DH / 128, NRT), 256, 0, stream>>>(xb, w1T, b1, rowtok, offs, hid);
    k_gemm2<<<dim3(DM / 128, NRT), 256, 0, stream>>>(hid, w2T, b2, roww, offs, outb);
    k_combine<<<NTOK, 256, 0, stream>>>(outb, slot, out);
    k_finalize<<<1, 1, 0, stream>>>(fcnt, sump, szent, out);
}

// Round 3
// 575.286 us; speedup vs baseline: 2.5977x; 1.0501x over previous
//
#include <hip/hip_runtime.h>
#include <hip/hip_bf16.h>

#define NTOK 8192
#define DM 1024
#define NE 8
#define DH 2048
#define CAP 17408   // 16384 + 8*128 padding, multiple of 128
#define NRT 136     // CAP/128

typedef __attribute__((ext_vector_type(8))) short short8;
typedef __attribute__((ext_vector_type(4))) float float4v;

// async global->LDS DMA, 16B per lane; LDS dest must be wave-uniform base + lane*16
#define ASYNC_COPY16(gsrc, ldst)                                                              \
    __builtin_amdgcn_global_load_lds((const __attribute__((address_space(1))) unsigned int*)(gsrc), \
                                     (__attribute__((address_space(3))) unsigned int*)(ldst), \
                                     16, 0, 0)

static __device__ __forceinline__ unsigned short f2bf(float f) {
    __hip_bfloat16 h = __float2bfloat16(f);
    return *reinterpret_cast<unsigned short*>(&h);
}

// ---------------- weight transpose: src [z][R][C] fp32 -> dst [z][C][R] bf16 ----------------
// 64x64 tiles; 256B coalesced loads, 128B-contiguous ushort4 stores; 2-way LDS aliasing only.

__global__ __launch_bounds__(256) void k_transpose(const float* __restrict__ src,
                                                   __hip_bfloat16* __restrict__ dst,
                                                   int R, int C) {
    __shared__ float t[64][65];
    size_t mat = (size_t)blockIdx.z * R * C;
    src += mat;
    dst += mat;
    int c0 = blockIdx.x * 64, r0 = blockIdx.y * 64;
    int tx = threadIdx.x & 63, ty = threadIdx.x >> 6;  // 64 x 4
#pragma unroll
    for (int i = 0; i < 16; i++) {
        int r = ty + i * 4;
        t[r][tx] = src[(size_t)(r0 + r) * C + c0 + tx];
    }
    __syncthreads();
    int rx = (threadIdx.x & 15) * 4;  // 0..60
    int cy = threadIdx.x >> 4;        // 0..15
#pragma unroll
    for (int i = 0; i < 4; i++) {
        int c = cy + i * 16;
        ushort4 v;
        v.x = f2bf(t[rx + 0][c]);
        v.y = f2bf(t[rx + 1][c]);
        v.z = f2bf(t[rx + 2][c]);
        v.w = f2bf(t[rx + 3][c]);
        *(ushort4*)((unsigned short*)dst + (size_t)(c0 + c) * R + r0 + rx) = v;
    }
}

// ---------------- router (atomic-free; also emits xb = bf16(x)) ----------------

__global__ __launch_bounds__(256) void k_router(const float* __restrict__ x,
                                                const float* __restrict__ rw,
                                                const float* __restrict__ rb,
                                                __hip_bfloat16* __restrict__ xb,
                                                int* __restrict__ topidx,
                                                float* __restrict__ topw,
                                                float* __restrict__ probs8,   // [NTOK][8]
                                                float* __restrict__ zent) {   // [NTOK][2]
    int lane = threadIdx.x & 63, wv = threadIdx.x >> 6;
    int n = blockIdx.x * 4 + wv;
    const float* xr = x + (size_t)n * DM;
    unsigned short* xbr = (unsigned short*)xb + (size_t)n * DM;
    float p[8] = {0.f, 0.f, 0.f, 0.f, 0.f, 0.f, 0.f, 0.f};
#pragma unroll
    for (int i = 0; i < 16; i++) {
        int d = lane + i * 64;
        float xv = xr[d];
        xbr[d] = f2bf(xv);
        const float4* w4 = (const float4*)(rw + (size_t)d * 8);
        float4 wa = w4[0], wb = w4[1];
        p[0] += xv * wa.x; p[1] += xv * wa.y; p[2] += xv * wa.z; p[3] += xv * wa.w;
        p[4] += xv * wb.x; p[5] += xv * wb.y; p[6] += xv * wb.z; p[7] += xv * wb.w;
    }
#pragma unroll
    for (int e = 0; e < 8; e++) {
#pragma unroll
        for (int off = 32; off > 0; off >>= 1) p[e] += __shfl_down(p[e], off);
    }
    if (lane == 0) {
        float logits[8], probs[8];
        float mx = -1e30f;
#pragma unroll
        for (int e = 0; e < 8; e++) {
            logits[e] = p[e] + rb[e];
            mx = fmaxf(mx, logits[e]);
        }
        float se = 0.f;
#pragma unroll
        for (int e = 0; e < 8; e++) {
            probs[e] = __expf(logits[e] - mx);
            se += probs[e];
        }
        float inv = 1.f / se;
        float z = mx + logf(se);
        float ent = 0.f;
#pragma unroll
        for (int e = 0; e < 8; e++) {
            probs[e] *= inv;
            ent -= probs[e] * logf(probs[e] + 1e-10f);
        }
        int i0 = 0;
#pragma unroll
        for (int e = 1; e < 8; e++)
            if (probs[e] > probs[i0]) i0 = e;
        int i1 = (i0 == 0) ? 1 : 0;
#pragma unroll
        for (int e = 0; e < 8; e++)
            if (e != i0 && e != i1 && probs[e] > probs[i1]) i1 = e;
        float w0 = probs[i0], w1v = probs[i1];
        float s = w0 + w1v + 1e-9f;
        topidx[2 * n] = i0;
        topidx[2 * n + 1] = i1;
        topw[2 * n] = w0 / s;
        topw[2 * n + 1] = w1v / s;
        float* pr = probs8 + (size_t)n * 8;
#pragma unroll
        for (int e = 0; e < 8; e++) pr[e] = probs[e];
        zent[2 * n] = z * z;
        zent[2 * n + 1] = ent;
    }
}

// ---------------- stats reduction ----------------

__global__ __launch_bounds__(256) void k_stats(const int* __restrict__ topidx,
                                               const float* __restrict__ probs8,
                                               const float* __restrict__ zent,
                                               float* __restrict__ fcnt,
                                               float* __restrict__ sump,
                                               float* __restrict__ szent) {
    int n = blockIdx.x * 256 + threadIdx.x;
    float v[18];
    int e0 = topidx[2 * n], e1 = topidx[2 * n + 1];
#pragma unroll
    for (int e = 0; e < 8; e++) v[e] = (float)((e == e0) + (e == e1));
    const float4* p4 = (const float4*)(probs8 + (size_t)n * 8);
    float4 pa = p4[0], pb = p4[1];
    v[8] = pa.x; v[9] = pa.y; v[10] = pa.z; v[11] = pa.w;
    v[12] = pb.x; v[13] = pb.y; v[14] = pb.z; v[15] = pb.w;
    v[16] = zent[2 * n];
    v[17] = zent[2 * n + 1];
#pragma unroll
    for (int i = 0; i < 18; i++)
#pragma unroll
        for (int off = 32; off > 0; off >>= 1) v[i] += __shfl_down(v[i], off);
    __shared__ float part[4][18];
    int lane = threadIdx.x & 63, wv = threadIdx.x >> 6;
    if (lane == 0)
#pragma unroll
        for (int i = 0; i < 18; i++) part[wv][i] = v[i];
    __syncthreads();
    if (threadIdx.x == 0) {
#pragma unroll
        for (int i = 0; i < 18; i++) {
            float s = part[0][i] + part[1][i] + part[2][i] + part[3][i];
            if (i < 8) atomicAdd(&fcnt[i], s);
            else if (i < 16) atomicAdd(&sump[i - 8], s);
            else atomicAdd(&szent[i - 16], s);
        }
    }
}

// ---------------- scan + scatter ----------------

__global__ void k_scan(const float* __restrict__ fcnt, int* __restrict__ offs) {
    if (threadIdx.x == 0 && blockIdx.x == 0) {
        int o = 0;
        for (int e = 0; e < NE; e++) {
            offs[e] = o;
            int c = (int)(fcnt[e] + 0.5f);
            o += (c + 127) & ~127;
        }
        offs[NE] = o;
    }
}

__global__ __launch_bounds__(256) void k_scatter(const int* __restrict__ topidx,
                                                 const float* __restrict__ topw,
                                                 const int* __restrict__ offs,
                                                 int* __restrict__ cnt2,
                                                 int* __restrict__ rowtok,
                                                 float* __restrict__ roww,
                                                 int* __restrict__ slot) {
    __shared__ int lcnt[8], lbase[8];
    int tid = threadIdx.x;
    if (tid < 8) lcnt[tid] = 0;
    __syncthreads();
    int n = blockIdx.x * 256 + tid;
    int e0 = topidx[2 * n], e1 = topidx[2 * n + 1];
    int p0 = atomicAdd(&lcnt[e0], 1);
    int p1 = atomicAdd(&lcnt[e1], 1);
    __syncthreads();
    if (tid < 8) lbase[tid] = atomicAdd(&cnt2[tid], lcnt[tid]);
    __syncthreads();
    int r0 = offs[e0] + lbase[e0] + p0;
    int r1 = offs[e1] + lbase[e1] + p1;
    rowtok[r0] = n; roww[r0] = topw[2 * n];     slot[2 * n] = r0;
    rowtok[r1] = n; roww[r1] = topw[2 * n + 1]; slot[2 * n + 1] = r1;
}

// ---------------- GEMM1: hidden = gelu(x_gathered @ w1 + b1), bf16 out ----------------
// XCD-swizzled 1D grid + double-buffered global_load_lds staging.

__global__ __launch_bounds__(256) void k_gemm1(const __hip_bfloat16* __restrict__ xb,
                                               const __hip_bfloat16* __restrict__ w1T,  // [E][H][D]
                                               const float* __restrict__ b1,            // [E][H]
                                               const int* __restrict__ rowtok,
                                               const int* __restrict__ offs,
                                               __hip_bfloat16* __restrict__ hid) {      // [CAP][DH]
    // 2176 blocks: xcd = bid&7 gets 17 row-tiles x 16 col-tiles, col fastest -> A-tile L2 reuse
    int bid = blockIdx.x;
    int i = bid >> 3;
    int row0 = ((bid & 7) * 17 + (i >> 4)) * 128;
    if (row0 >= offs[NE]) return;
    int h0 = (i & 15) * 128;
    int e = 0;
    while (row0 >= offs[e + 1]) e++;
    int tid = threadIdx.x;

    __shared__ __align__(16) short A_lds[2][4096];
    __shared__ __align__(16) short B_lds[2][4096];
    __shared__ int tokoff[128];
    if (tid < 128) {
        int t = rowtok[row0 + tid];
        tokoff[tid] = (t < 0 ? 0 : t) * DM;  // pad rows compute on token 0 (output unused)
    }
    __syncthreads();

    int m = tid & 127, kg = tid >> 7;  // kg in {0,1}
    const short* asrc = (const short*)xb + tokoff[m] + kg * 8;
    const short* bsrc = (const short*)w1T + ((size_t)e * DH + h0 + m) * DM + kg * 8;
    int w0off = (kg * 128 + m) * 8;        // lane-contiguous: base + lane*16B per wave
    int w1off = ((kg + 2) * 128 + m) * 8;

    int lane = tid & 63, wv = tid >> 6;
    int wm = (wv >> 1) * 64, wn = (wv & 1) * 64;
    int quad = lane >> 4, l16 = lane & 15;
    int a_off[4], b_off[4];
#pragma unroll
    for (int t = 0; t < 4; t++) {
        a_off[t] = (quad * 128 + wm + t * 16 + l16) * 8;
        b_off[t] = (quad * 128 + wn + t * 16 + l16) * 8;
    }
    float4v acc[4][4];
#pragma unroll
    for (int i2 = 0; i2 < 4; i2++)
#pragma unroll
        for (int j = 0; j < 4; j++) {
            float4v z = {0.f, 0.f, 0.f, 0.f};
            acc[i2][j] = z;
        }

    // stage tile 'it' into buffer it&1
    ASYNC_COPY16(asrc, &A_lds[0][w0off]);
    ASYNC_COPY16(asrc + 16, &A_lds[0][w1off]);
    ASYNC_COPY16(bsrc, &B_lds[0][w0off]);
    ASYNC_COPY16(bsrc + 16, &B_lds[0][w1off]);
#pragma unroll 1
    for (int it = 0; it < DM / 32; ++it) {
        __syncthreads();  // drains vmcnt(0): buffer it&1 ready; prev compute's ds_reads done
        if (it + 1 < DM / 32) {
            int k0 = (it + 1) * 32, nb = (it + 1) & 1;
            ASYNC_COPY16(asrc + k0, &A_lds[nb][w0off]);
            ASYNC_COPY16(asrc + k0 + 16, &A_lds[nb][w1off]);
            ASYNC_COPY16(bsrc + k0, &B_lds[nb][w0off]);
            ASYNC_COPY16(bsrc + k0 + 16, &B_lds[nb][w1off]);
        }
        int buf = it & 1;
#pragma unroll
        for (int mt = 0; mt < 4; mt++) {
            short8 a = *(const short8*)&A_lds[buf][a_off[mt]];
#pragma unroll
            for (int nt = 0; nt < 4; nt++) {
                short8 b = *(const short8*)&B_lds[buf][b_off[nt]];
                acc[mt][nt] = __builtin_amdgcn_mfma_f32_16x16x32_bf16(a, b, acc[mt][nt], 0, 0, 0);
            }
        }
    }

    const float* b1e = b1 + (size_t)e * DH + h0;
#pragma unroll
    for (int mt = 0; mt < 4; mt++) {
#pragma unroll
        for (int nt = 0; nt < 4; nt++) {
            int rl = wm + mt * 16 + quad * 4;
            int cl = wn + nt * 16 + l16;
            float bias = b1e[cl];
#pragma unroll
            for (int r = 0; r < 4; r++) {
                float v = acc[mt][nt][r] + bias;
                v = 0.5f * v * (1.0f + erff(v * 0.70710678118654752f));  // exact gelu
                hid[(size_t)(row0 + rl + r) * DH + h0 + cl] = __float2bfloat16(v);
            }
        }
    }
}

// ---------------- GEMM2: outb = (hidden @ w2 + b2) * weight, fp32 out ----------------

__global__ __launch_bounds__(256) void k_gemm2(const __hip_bfloat16* __restrict__ hid,  // [CAP][DH]
                                               const __hip_bfloat16* __restrict__ w2T,  // [E][D][H]
                                               const float* __restrict__ b2,            // [E][D]
                                               const float* __restrict__ roww,
                                               const int* __restrict__ offs,
                                               float* __restrict__ outb) {              // [CAP][DM]
    // 1088 blocks: xcd = bid&7 gets 17 row-tiles x 8 col-tiles, col fastest
    int bid = blockIdx.x;
    int i = bid >> 3;
    int row0 = ((bid & 7) * 17 + (i >> 3)) * 128;
    if (row0 >= offs[NE]) return;
    int d0 = (i & 7) * 128;
    int e = 0;
    while (row0 >= offs[e + 1]) e++;
    int tid = threadIdx.x;

    __shared__ __align__(16) short A_lds[2][4096];
    __shared__ __align__(16) short B_lds[2][4096];

    int m = tid & 127, kg = tid >> 7;
    const short* asrc = (const short*)hid + (size_t)(row0 + m) * DH + kg * 8;
    const short* bsrc = (const short*)w2T + ((size_t)e * DM + d0 + m) * DH + kg * 8;
    int w0off = (kg * 128 + m) * 8;
    int w1off = ((kg + 2) * 128 + m) * 8;

    int lane = tid & 63, wv = tid >> 6;
    int wm = (wv >> 1) * 64, wn = (wv & 1) * 64;
    int quad = lane >> 4, l16 = lane & 15;
    int a_off[4], b_off[4];
#pragma unroll
    for (int t = 0; t < 4; t++) {
        a_off[t] = (quad * 128 + wm + t * 16 + l16) * 8;
        b_off[t] = (quad * 128 + wn + t * 16 + l16) * 8;
    }
    float4v acc[4][4];
#pragma unroll
    for (int i2 = 0; i2 < 4; i2++)
#pragma unroll
        for (int j = 0; j < 4; j++) {
            float4v z = {0.f, 0.f, 0.f, 0.f};
            acc[i2][j] = z;
        }

    ASYNC_COPY16(asrc, &A_lds[0][w0off]);
    ASYNC_COPY16(asrc + 16, &A_lds[0][w1off]);
    ASYNC_COPY16(bsrc, &B_lds[0][w0off]);
    ASYNC_COPY16(bsrc + 16, &B_lds[0][w1off]);
#pragma unroll 1
    for (int it = 0; it < DH / 32; ++it) {
        __syncthreads();
        if (it + 1 < DH / 32) {
            int k0 = (it + 1) * 32, nb = (it + 1) & 1;
            ASYNC_COPY16(asrc + k0, &A_lds[nb][w0off]);
            ASYNC_COPY16(asrc + k0 + 16, &A_lds[nb][w1off]);
            ASYNC_COPY16(bsrc + k0, &B_lds[nb][w0off]);
            ASYNC_COPY16(bsrc + k0 + 16, &B_lds[nb][w1off]);
        }
        int buf = it & 1;
#pragma unroll
        for (int mt = 0; mt < 4; mt++) {
            short8 a = *(const short8*)&A_lds[buf][a_off[mt]];
#pragma unroll
            for (int nt = 0; nt < 4; nt++) {
                short8 b = *(const short8*)&B_lds[buf][b_off[nt]];
                acc[mt][nt] = __builtin_amdgcn_mfma_f32_16x16x32_bf16(a, b, acc[mt][nt], 0, 0, 0);
            }
        }
    }

    const float* b2e = b2 + (size_t)e * DM + d0;
#pragma unroll
    for (int mt = 0; mt < 4; mt++) {
#pragma unroll
        for (int nt = 0; nt < 4; nt++) {
            int rl = wm + mt * 16 + quad * 4;
            int cl = wn + nt * 16 + l16;
            float bias = b2e[cl];
#pragma unroll
            for (int r = 0; r < 4; r++) {
                int grow = row0 + rl + r;
                float v = (acc[mt][nt][r] + bias) * roww[grow];
                outb[(size_t)grow * DM + d0 + cl] = v;
            }
        }
    }
}

// ---------------- combine + finalize ----------------

__global__ __launch_bounds__(256) void k_combine(const float* __restrict__ outb,
                                                 const int* __restrict__ slot,
                                                 float* __restrict__ y) {
    int n = blockIdx.x;
    int r0 = slot[2 * n], r1 = slot[2 * n + 1];
    const float4* p0 = (const float4*)(outb + (size_t)r0 * DM);
    const float4* p1 = (const float4*)(outb + (size_t)r1 * DM);
    float4 a = p0[threadIdx.x], b = p1[threadIdx.x];
    float4 c;
    c.x = a.x + b.x;
    c.y = a.y + b.y;
    c.z = a.z + b.z;
    c.w = a.w + b.w;
    ((float4*)(y + (size_t)n * DM))[threadIdx.x] = c;
}

__global__ void k_finalize(const float* __restrict__ fcnt, const float* __restrict__ sump,
                           const float* __restrict__ szent, float* __restrict__ out) {
    if (threadIdx.x == 0 && blockIdx.x == 0) {
        const float invN = 1.0f / (float)NTOK;
        float lb = 0.f;
        float f[NE], P[NE];
        for (int e = 0; e < NE; e++) {
            f[e] = fcnt[e] * invN;
            P[e] = sump[e] * invN;
            lb += f[e] * P[e];
        }
        size_t base = (size_t)NTOK * DM;
        out[base + 0] = -(float)NE * lb;      // lb_loss
        out[base + 1] = szent[0] * invN;      // z_loss
        out[base + 2] = szent[1] * invN;      // entropy
        for (int e = 0; e < NE; e++) out[base + 3 + e] = f[e];
        for (int e = 0; e < NE; e++) out[base + 11 + e] = P[e];
    }
}

// ---------------- launch ----------------

extern "C" void kernel_launch(void* const* d_in, const int* in_sizes, int n_in,
                              void* d_out, int out_size, void* d_ws, size_t ws_size,
                              hipStream_t stream) {
    const float* x  = (const float*)d_in[0];
    const float* rw = (const float*)d_in[1];
    const float* rb = (const float*)d_in[2];
    const float* w1 = (const float*)d_in[3];
    const float* b1 = (const float*)d_in[4];
    const float* w2 = (const float*)d_in[5];
    const float* b2 = (const float*)d_in[6];
    float* out = (float*)d_out;

    char* ws = (char*)d_ws;
    size_t o = 0;
    auto alloc = [&](size_t bytes) {
        size_t r = o;
        o = (o + bytes + 255) & ~(size_t)255;
        return r;
    };
    __hip_bfloat16* w1T = (__hip_bfloat16*)(ws + alloc((size_t)NE * DM * DH * 2));
    __hip_bfloat16* w2T = (__hip_bfloat16*)(ws + alloc((size_t)NE * DM * DH * 2));
    __hip_bfloat16* xb  = (__hip_bfloat16*)(ws + alloc((size_t)NTOK * DM * 2));
    __hip_bfloat16* hid = (__hip_bfloat16*)(ws + alloc((size_t)CAP * DH * 2));
    float* outb = (float*)(ws + alloc((size_t)CAP * DM * 4));
    int* rowtok = (int*)(ws + alloc(CAP * 4));
    size_t zstart = o;
    float* roww  = (float*)(ws + alloc(CAP * 4));
    float* fcnt  = (float*)(ws + alloc(64));
    int* cnt2    = (int*)(ws + alloc(64));
    int* offs    = (int*)(ws + alloc(64));
    float* sump  = (float*)(ws + alloc(64));
    float* szent = (float*)(ws + alloc(64));
    size_t zend = o;
    int* topidx = (int*)(ws + alloc((size_t)NTOK * 2 * 4));
    float* topw = (float*)(ws + alloc((size_t)NTOK * 2 * 4));
    int* slot   = (int*)(ws + alloc((size_t)NTOK * 2 * 4));
    float* probs8 = (float*)(ws + alloc((size_t)NTOK * 8 * 4));
    float* zent   = (float*)(ws + alloc((size_t)NTOK * 2 * 4));

    hipMemsetAsync(rowtok, 0xFF, (size_t)CAP * 4, stream);   // pad rows -> token -1
    hipMemsetAsync(ws + zstart, 0, zend - zstart, stream);   // weights/counters/stats

    k_transpose<<<dim3(DH / 64, DM / 64, NE), 256, 0, stream>>>(w1, w1T, DM, DH);  // -> [E][H][D]
    k_transpose<<<dim3(DM / 64, DH / 64, NE), 256, 0, stream>>>(w2, w2T, DH, DM);  // -> [E][D][H]
    k_router<<<NTOK / 4, 256, 0, stream>>>(x, rw, rb, xb, topidx, topw, probs8, zent);
    k_stats<<<NTOK / 256, 256, 0, stream>>>(topidx, probs8, zent, fcnt, sump, szent);
    k_scan<<<1, 1, 0, stream>>>(fcnt, offs);
    k_scatter<<<NTOK / 256, 256, 0, stream>>>(topidx, topw, offs, cnt2, rowtok, roww, slot);
    k_gemm1<<<16 * NRT, 256, 0, stream>>>(xb, w1T, b1, rowtok, offs, hid);
    k_gemm2<<<8 * NRT, 256, 0, stream>>>(hid, w2T, b2, roww, offs, outb);
    k_combine<<<NTOK, 256, 0, stream>>>(outb, slot, out);
    k_finalize<<<1, 1, 0, stream>>>(fcnt, sump, szent, out);
}

// Round 4
// 465.561 us; speedup vs baseline: 3.2099x; 1.2357x over previous
//
#include <hip/hip_runtime.h>
#include <hip/hip_bf16.h>

#define NTOK 8192
#define DM 1024
#define NE 8
#define DH 2048
#define CAP 17408   // 16384 + 8*128 padding, multiple of 128
#define NRT 136     // CAP/128

typedef __attribute__((ext_vector_type(8))) short short8;
typedef __attribute__((ext_vector_type(4))) float float4v;

// async global->LDS DMA, 16B per lane; LDS dest is wave-uniform base + lane*16
#define ASYNC_COPY16(gsrc, ldst)                                                              \
    __builtin_amdgcn_global_load_lds((const __attribute__((address_space(1))) unsigned int*)(gsrc), \
                                     (__attribute__((address_space(3))) unsigned int*)(ldst), \
                                     16, 0, 0)

static __device__ __forceinline__ unsigned short f2bf(float f) {
    __hip_bfloat16 h = __float2bfloat16(f);
    return *reinterpret_cast<unsigned short*>(&h);
}

// branch-free gelu, exact-erf form via Abramowitz-Stegun 7.1.26 (|err| < 1.5e-7)
static __device__ __forceinline__ float fast_gelu(float v) {
    float x = v * 0.70710678118654752f;
    float ax = fabsf(x);
    float t = __frcp_rn(1.0f + 0.3275911f * ax);
    float poly = ((((1.061405429f * t - 1.453152027f) * t + 1.421413741f) * t
                   - 0.284496736f) * t + 0.254829592f) * t;
    float y = 1.0f - poly * __expf(-ax * ax);   // erf(|x|)
    float erfv = copysignf(y, x);
    return 0.5f * v * (1.0f + erfv);
}

// ---------------- weight transpose: src [z][R][C] fp32 -> dst [z][C][R] bf16 ----------------

__global__ __launch_bounds__(256) void k_transpose(const float* __restrict__ src,
                                                   __hip_bfloat16* __restrict__ dst,
                                                   int R, int C) {
    __shared__ float t[64][65];
    size_t mat = (size_t)blockIdx.z * R * C;
    src += mat;
    dst += mat;
    int c0 = blockIdx.x * 64, r0 = blockIdx.y * 64;
    int tx = threadIdx.x & 63, ty = threadIdx.x >> 6;  // 64 x 4
#pragma unroll
    for (int i = 0; i < 16; i++) {
        int r = ty + i * 4;
        t[r][tx] = src[(size_t)(r0 + r) * C + c0 + tx];
    }
    __syncthreads();
    int rx = (threadIdx.x & 15) * 4;  // 0..60
    int cy = threadIdx.x >> 4;        // 0..15
#pragma unroll
    for (int i = 0; i < 4; i++) {
        int c = cy + i * 16;
        ushort4 v;
        v.x = f2bf(t[rx + 0][c]);
        v.y = f2bf(t[rx + 1][c]);
        v.z = f2bf(t[rx + 2][c]);
        v.w = f2bf(t[rx + 3][c]);
        *(ushort4*)((unsigned short*)dst + (size_t)(c0 + c) * R + r0 + rx) = v;
    }
}

// ---------------- router (atomic-free; also emits xb = bf16(x)) ----------------

__global__ __launch_bounds__(256) void k_router(const float* __restrict__ x,
                                                const float* __restrict__ rw,
                                                const float* __restrict__ rb,
                                                __hip_bfloat16* __restrict__ xb,
                                                int* __restrict__ topidx,
                                                float* __restrict__ topw,
                                                float* __restrict__ probs8,   // [NTOK][8]
                                                float* __restrict__ zent) {   // [NTOK][2]
    int lane = threadIdx.x & 63, wv = threadIdx.x >> 6;
    int n = blockIdx.x * 4 + wv;
    const float* xr = x + (size_t)n * DM;
    unsigned short* xbr = (unsigned short*)xb + (size_t)n * DM;
    float p[8] = {0.f, 0.f, 0.f, 0.f, 0.f, 0.f, 0.f, 0.f};
#pragma unroll
    for (int i = 0; i < 16; i++) {
        int d = lane + i * 64;
        float xv = xr[d];
        xbr[d] = f2bf(xv);
        const float4* w4 = (const float4*)(rw + (size_t)d * 8);
        float4 wa = w4[0], wb = w4[1];
        p[0] += xv * wa.x; p[1] += xv * wa.y; p[2] += xv * wa.z; p[3] += xv * wa.w;
        p[4] += xv * wb.x; p[5] += xv * wb.y; p[6] += xv * wb.z; p[7] += xv * wb.w;
    }
#pragma unroll
    for (int e = 0; e < 8; e++) {
#pragma unroll
        for (int off = 32; off > 0; off >>= 1) p[e] += __shfl_down(p[e], off);
    }
    if (lane == 0) {
        float logits[8], probs[8];
        float mx = -1e30f;
#pragma unroll
        for (int e = 0; e < 8; e++) {
            logits[e] = p[e] + rb[e];
            mx = fmaxf(mx, logits[e]);
        }
        float se = 0.f;
#pragma unroll
        for (int e = 0; e < 8; e++) {
            probs[e] = __expf(logits[e] - mx);
            se += probs[e];
        }
        float inv = 1.f / se;
        float z = mx + logf(se);
        float ent = 0.f;
#pragma unroll
        for (int e = 0; e < 8; e++) {
            probs[e] *= inv;
            ent -= probs[e] * logf(probs[e] + 1e-10f);
        }
        int i0 = 0;
#pragma unroll
        for (int e = 1; e < 8; e++)
            if (probs[e] > probs[i0]) i0 = e;
        int i1 = (i0 == 0) ? 1 : 0;
#pragma unroll
        for (int e = 0; e < 8; e++)
            if (e != i0 && e != i1 && probs[e] > probs[i1]) i1 = e;
        float w0 = probs[i0], w1v = probs[i1];
        float s = w0 + w1v + 1e-9f;
        topidx[2 * n] = i0;
        topidx[2 * n + 1] = i1;
        topw[2 * n] = w0 / s;
        topw[2 * n + 1] = w1v / s;
        float* pr = probs8 + (size_t)n * 8;
#pragma unroll
        for (int e = 0; e < 8; e++) pr[e] = probs[e];
        zent[2 * n] = z * z;
        zent[2 * n + 1] = ent;
    }
}

// ---------------- stats reduction ----------------

__global__ __launch_bounds__(256) void k_stats(const int* __restrict__ topidx,
                                               const float* __restrict__ probs8,
                                               const float* __restrict__ zent,
                                               float* __restrict__ fcnt,
                                               float* __restrict__ sump,
                                               float* __restrict__ szent) {
    int n = blockIdx.x * 256 + threadIdx.x;
    float v[18];
    int e0 = topidx[2 * n], e1 = topidx[2 * n + 1];
#pragma unroll
    for (int e = 0; e < 8; e++) v[e] = (float)((e == e0) + (e == e1));
    const float4* p4 = (const float4*)(probs8 + (size_t)n * 8);
    float4 pa = p4[0], pb = p4[1];
    v[8] = pa.x; v[9] = pa.y; v[10] = pa.z; v[11] = pa.w;
    v[12] = pb.x; v[13] = pb.y; v[14] = pb.z; v[15] = pb.w;
    v[16] = zent[2 * n];
    v[17] = zent[2 * n + 1];
#pragma unroll
    for (int i = 0; i < 18; i++)
#pragma unroll
        for (int off = 32; off > 0; off >>= 1) v[i] += __shfl_down(v[i], off);
    __shared__ float part[4][18];
    int lane = threadIdx.x & 63, wv = threadIdx.x >> 6;
    if (lane == 0)
#pragma unroll
        for (int i = 0; i < 18; i++) part[wv][i] = v[i];
    __syncthreads();
    if (threadIdx.x == 0) {
#pragma unroll
        for (int i = 0; i < 18; i++) {
            float s = part[0][i] + part[1][i] + part[2][i] + part[3][i];
            if (i < 8) atomicAdd(&fcnt[i], s);
            else if (i < 16) atomicAdd(&sump[i - 8], s);
            else atomicAdd(&szent[i - 16], s);
        }
    }
}

// ---------------- scan + scatter ----------------

__global__ void k_scan(const float* __restrict__ fcnt, int* __restrict__ offs) {
    if (threadIdx.x == 0 && blockIdx.x == 0) {
        int o = 0;
        for (int e = 0; e < NE; e++) {
            offs[e] = o;
            int c = (int)(fcnt[e] + 0.5f);
            o += (c + 127) & ~127;
        }
        offs[NE] = o;
    }
}

__global__ __launch_bounds__(256) void k_scatter(const int* __restrict__ topidx,
                                                 const float* __restrict__ topw,
                                                 const int* __restrict__ offs,
                                                 int* __restrict__ cnt2,
                                                 int* __restrict__ rowtok,
                                                 float* __restrict__ roww,
                                                 int* __restrict__ slot) {
    __shared__ int lcnt[8], lbase[8];
    int tid = threadIdx.x;
    if (tid < 8) lcnt[tid] = 0;
    __syncthreads();
    int n = blockIdx.x * 256 + tid;
    int e0 = topidx[2 * n], e1 = topidx[2 * n + 1];
    int p0 = atomicAdd(&lcnt[e0], 1);
    int p1 = atomicAdd(&lcnt[e1], 1);
    __syncthreads();
    if (tid < 8) lbase[tid] = atomicAdd(&cnt2[tid], lcnt[tid]);
    __syncthreads();
    int r0 = offs[e0] + lbase[e0] + p0;
    int r1 = offs[e1] + lbase[e1] + p1;
    rowtok[r0] = n; roww[r0] = topw[2 * n];     slot[2 * n] = r0;
    rowtok[r1] = n; roww[r1] = topw[2 * n + 1]; slot[2 * n + 1] = r1;
}

// ---------------- GEMM1: hidden = gelu(x_gathered @ w1 + b1), bf16 out ----------------
// LDS tiles row-major [128][32] with XOR chunk swizzle p = q ^ ((row>>1)&3):
//  - DMA: 4 consecutive lanes read one fully-used 64B line (coalesced), dest = uniform + lane*16
//  - ds_read_b128 fragments: uniform 8 dwords/bank (b128 minimum), 2-way aliasing only

__global__ __launch_bounds__(256) void k_gemm1(const __hip_bfloat16* __restrict__ xb,
                                               const __hip_bfloat16* __restrict__ w1T,  // [E][H][D]
                                               const float* __restrict__ b1,            // [E][H]
                                               const int* __restrict__ rowtok,
                                               const int* __restrict__ offs,
                                               __hip_bfloat16* __restrict__ hid) {      // [CAP][DH]
    // 2176 blocks: xcd = bid&7 gets 17 row-tiles x 16 col-tiles, col fastest -> A-tile L2 reuse
    int bid = blockIdx.x;
    int ib = bid >> 3;
    int row0 = ((bid & 7) * 17 + (ib >> 4)) * 128;
    if (row0 >= offs[NE]) return;
    int h0 = (ib & 15) * 128;
    int e = 0;
    while (row0 >= offs[e + 1]) e++;
    int tid = threadIdx.x;

    __shared__ __align__(16) short A_lds[2][4096];
    __shared__ __align__(16) short B_lds[2][4096];
    __shared__ int tokoff[128];
    if (tid < 128) {
        int t = rowtok[row0 + tid];
        tokoff[tid] = (t < 0 ? 0 : t) * DM;  // pad rows compute on token 0 (output unused)
    }
    __syncthreads();

    int lane = tid & 63, wv = tid >> 6;
    // staging map: lane -> (local row, 16B chunk)
    int lr = lane >> 2, pc = lane & 3;
    int ra = wv * 16 + lr;            // rows 0..63
    int rbr = ra + 64;                // rows 64..127; ((rbr>>1)&3) == ((ra>>1)&3)
    int ch = pc ^ ((ra >> 1) & 3);    // global chunk for this physical slot
    const short* a0 = (const short*)xb + tokoff[ra] + ch * 8;
    const short* a1 = (const short*)xb + tokoff[rbr] + ch * 8;
    const short* bs0 = (const short*)w1T + ((size_t)e * DH + h0 + ra) * DM + ch * 8;
    const short* bs1 = (const short*)w1T + ((size_t)e * DH + h0 + rbr) * DM + ch * 8;
    int ld0 = ra * 32 + pc * 8;       // shorts; == wv*512 + lane*8 (uniform + lane*16B)
    int ld1 = rbr * 32 + pc * 8;

    int wm = (wv >> 1) * 64, wn = (wv & 1) * 64;
    int quad = lane >> 4, l16 = lane & 15;
    int a_off[4], b_off[4];
#pragma unroll
    for (int t = 0; t < 4; t++) {
        int arow = wm + t * 16 + l16;
        a_off[t] = arow * 32 + ((quad ^ ((arow >> 1) & 3)) * 8);
        int bcol = wn + t * 16 + l16;
        b_off[t] = bcol * 32 + ((quad ^ ((bcol >> 1) & 3)) * 8);
    }
    float4v acc[4][4];
#pragma unroll
    for (int i2 = 0; i2 < 4; i2++)
#pragma unroll
        for (int j = 0; j < 4; j++) {
            float4v z = {0.f, 0.f, 0.f, 0.f};
            acc[i2][j] = z;
        }

    ASYNC_COPY16(a0, &A_lds[0][ld0]);
    ASYNC_COPY16(a1, &A_lds[0][ld1]);
    ASYNC_COPY16(bs0, &B_lds[0][ld0]);
    ASYNC_COPY16(bs1, &B_lds[0][ld1]);
#pragma unroll 1
    for (int it = 0; it < DM / 32; ++it) {
        __syncthreads();  // drains vmcnt(0): buffer it&1 ready; prev compute's ds_reads done
        if (it + 1 < DM / 32) {
            int k0 = (it + 1) * 32, nb = (it + 1) & 1;
            ASYNC_COPY16(a0 + k0, &A_lds[nb][ld0]);
            ASYNC_COPY16(a1 + k0, &A_lds[nb][ld1]);
            ASYNC_COPY16(bs0 + k0, &B_lds[nb][ld0]);
            ASYNC_COPY16(bs1 + k0, &B_lds[nb][ld1]);
        }
        int buf = it & 1;
#pragma unroll
        for (int mt = 0; mt < 4; mt++) {
            short8 a = *(const short8*)&A_lds[buf][a_off[mt]];
#pragma unroll
            for (int nt = 0; nt < 4; nt++) {
                short8 b = *(const short8*)&B_lds[buf][b_off[nt]];
                acc[mt][nt] = __builtin_amdgcn_mfma_f32_16x16x32_bf16(a, b, acc[mt][nt], 0, 0, 0);
            }
        }
    }

    const float* b1e = b1 + (size_t)e * DH + h0;
#pragma unroll
    for (int mt = 0; mt < 4; mt++) {
#pragma unroll
        for (int nt = 0; nt < 4; nt++) {
            int rl = wm + mt * 16 + quad * 4;
            int cl = wn + nt * 16 + l16;
            float bias = b1e[cl];
#pragma unroll
            for (int r = 0; r < 4; r++) {
                float v = fast_gelu(acc[mt][nt][r] + bias);
                hid[(size_t)(row0 + rl + r) * DH + h0 + cl] = __float2bfloat16(v);
            }
        }
    }
}

// ---------------- GEMM2: outb = (hidden @ w2 + b2) * weight, fp32 out ----------------

__global__ __launch_bounds__(256) void k_gemm2(const __hip_bfloat16* __restrict__ hid,  // [CAP][DH]
                                               const __hip_bfloat16* __restrict__ w2T,  // [E][D][H]
                                               const float* __restrict__ b2,            // [E][D]
                                               const float* __restrict__ roww,
                                               const int* __restrict__ offs,
                                               float* __restrict__ outb) {              // [CAP][DM]
    // 1088 blocks: xcd = bid&7 gets 17 row-tiles x 8 col-tiles, col fastest
    int bid = blockIdx.x;
    int ib = bid >> 3;
    int row0 = ((bid & 7) * 17 + (ib >> 3)) * 128;
    if (row0 >= offs[NE]) return;
    int d0 = (ib & 7) * 128;
    int e = 0;
    while (row0 >= offs[e + 1]) e++;
    int tid = threadIdx.x;

    __shared__ __align__(16) short A_lds[2][4096];
    __shared__ __align__(16) short B_lds[2][4096];

    int lane = tid & 63, wv = tid >> 6;
    int lr = lane >> 2, pc = lane & 3;
    int ra = wv * 16 + lr;
    int rbr = ra + 64;
    int ch = pc ^ ((ra >> 1) & 3);
    const short* a0 = (const short*)hid + (size_t)(row0 + ra) * DH + ch * 8;
    const short* a1 = (const short*)hid + (size_t)(row0 + rbr) * DH + ch * 8;
    const short* bs0 = (const short*)w2T + ((size_t)e * DM + d0 + ra) * DH + ch * 8;
    const short* bs1 = (const short*)w2T + ((size_t)e * DM + d0 + rbr) * DH + ch * 8;
    int ld0 = ra * 32 + pc * 8;
    int ld1 = rbr * 32 + pc * 8;

    int wm = (wv >> 1) * 64, wn = (wv & 1) * 64;
    int quad = lane >> 4, l16 = lane & 15;
    int a_off[4], b_off[4];
#pragma unroll
    for (int t = 0; t < 4; t++) {
        int arow = wm + t * 16 + l16;
        a_off[t] = arow * 32 + ((quad ^ ((arow >> 1) & 3)) * 8);
        int bcol = wn + t * 16 + l16;
        b_off[t] = bcol * 32 + ((quad ^ ((bcol >> 1) & 3)) * 8);
    }
    float4v acc[4][4];
#pragma unroll
    for (int i2 = 0; i2 < 4; i2++)
#pragma unroll
        for (int j = 0; j < 4; j++) {
            float4v z = {0.f, 0.f, 0.f, 0.f};
            acc[i2][j] = z;
        }

    ASYNC_COPY16(a0, &A_lds[0][ld0]);
    ASYNC_COPY16(a1, &A_lds[0][ld1]);
    ASYNC_COPY16(bs0, &B_lds[0][ld0]);
    ASYNC_COPY16(bs1, &B_lds[0][ld1]);
#pragma unroll 1
    for (int it = 0; it < DH / 32; ++it) {
        __syncthreads();
        if (it + 1 < DH / 32) {
            int k0 = (it + 1) * 32, nb = (it + 1) & 1;
            ASYNC_COPY16(a0 + k0, &A_lds[nb][ld0]);
            ASYNC_COPY16(a1 + k0, &A_lds[nb][ld1]);
            ASYNC_COPY16(bs0 + k0, &B_lds[nb][ld0]);
            ASYNC_COPY16(bs1 + k0, &B_lds[nb][ld1]);
        }
        int buf = it & 1;
#pragma unroll
        for (int mt = 0; mt < 4; mt++) {
            short8 a = *(const short8*)&A_lds[buf][a_off[mt]];
#pragma unroll
            for (int nt = 0; nt < 4; nt++) {
                short8 b = *(const short8*)&B_lds[buf][b_off[nt]];
                acc[mt][nt] = __builtin_amdgcn_mfma_f32_16x16x32_bf16(a, b, acc[mt][nt], 0, 0, 0);
            }
        }
    }

    const float* b2e = b2 + (size_t)e * DM + d0;
#pragma unroll
    for (int mt = 0; mt < 4; mt++) {
#pragma unroll
        for (int nt = 0; nt < 4; nt++) {
            int rl = wm + mt * 16 + quad * 4;
            int cl = wn + nt * 16 + l16;
            float bias = b2e[cl];
#pragma unroll
            for (int r = 0; r < 4; r++) {
                int grow = row0 + rl + r;
                float v = (acc[mt][nt][r] + bias) * roww[grow];
                outb[(size_t)grow * DM + d0 + cl] = v;
            }
        }
    }
}

// ---------------- combine + finalize ----------------

__global__ __launch_bounds__(256) void k_combine(const float* __restrict__ outb,
                                                 const int* __restrict__ slot,
                                                 float* __restrict__ y) {
    int n = blockIdx.x;
    int r0 = slot[2 * n], r1 = slot[2 * n + 1];
    const float4* p0 = (const float4*)(outb + (size_t)r0 * DM);
    const float4* p1 = (const float4*)(outb + (size_t)r1 * DM);
    float4 a = p0[threadIdx.x], b = p1[threadIdx.x];
    float4 c;
    c.x = a.x + b.x;
    c.y = a.y + b.y;
    c.z = a.z + b.z;
    c.w = a.w + b.w;
    ((float4*)(y + (size_t)n * DM))[threadIdx.x] = c;
}

__global__ void k_finalize(const float* __restrict__ fcnt, const float* __restrict__ sump,
                           const float* __restrict__ szent, float* __restrict__ out) {
    if (threadIdx.x == 0 && blockIdx.x == 0) {
        const float invN = 1.0f / (float)NTOK;
        float lb = 0.f;
        float f[NE], P[NE];
        for (int e = 0; e < NE; e++) {
            f[e] = fcnt[e] * invN;
            P[e] = sump[e] * invN;
            lb += f[e] * P[e];
        }
        size_t base = (size_t)NTOK * DM;
        out[base + 0] = -(float)NE * lb;      // lb_loss
        out[base + 1] = szent[0] * invN;      // z_loss
        out[base + 2] = szent[1] * invN;      // entropy
        for (int e = 0; e < NE; e++) out[base + 3 + e] = f[e];
        for (int e = 0; e < NE; e++) out[base + 11 + e] = P[e];
    }
}

// ---------------- launch ----------------

extern "C" void kernel_launch(void* const* d_in, const int* in_sizes, int n_in,
                              void* d_out, int out_size, void* d_ws, size_t ws_size,
                              hipStream_t stream) {
    const float* x  = (const float*)d_in[0];
    const float* rw = (const float*)d_in[1];
    const float* rb = (const float*)d_in[2];
    const float* w1 = (const float*)d_in[3];
    const float* b1 = (const float*)d_in[4];
    const float* w2 = (const float*)d_in[5];
    const float* b2 = (const float*)d_in[6];
    float* out = (float*)d_out;

    char* ws = (char*)d_ws;
    size_t o = 0;
    auto alloc = [&](size_t bytes) {
        size_t r = o;
        o = (o + bytes + 255) & ~(size_t)255;
        return r;
    };
    __hip_bfloat16* w1T = (__hip_bfloat16*)(ws + alloc((size_t)NE * DM * DH * 2));
    __hip_bfloat16* w2T = (__hip_bfloat16*)(ws + alloc((size_t)NE * DM * DH * 2));
    __hip_bfloat16* xb  = (__hip_bfloat16*)(ws + alloc((size_t)NTOK * DM * 2));
    __hip_bfloat16* hid = (__hip_bfloat16*)(ws + alloc((size_t)CAP * DH * 2));
    float* outb = (float*)(ws + alloc((size_t)CAP * DM * 4));
    int* rowtok = (int*)(ws + alloc(CAP * 4));
    size_t zstart = o;
    float* roww  = (float*)(ws + alloc(CAP * 4));
    float* fcnt  = (float*)(ws + alloc(64));
    int* cnt2    = (int*)(ws + alloc(64));
    int* offs    = (int*)(ws + alloc(64));
    float* sump  = (float*)(ws + alloc(64));
    float* szent = (float*)(ws + alloc(64));
    size_t zend = o;
    int* topidx = (int*)(ws + alloc((size_t)NTOK * 2 * 4));
    float* topw = (float*)(ws + alloc((size_t)NTOK * 2 * 4));
    int* slot   = (int*)(ws + alloc((size_t)NTOK * 2 * 4));
    float* probs8 = (float*)(ws + alloc((size_t)NTOK * 8 * 4));
    float* zent   = (float*)(ws + alloc((size_t)NTOK * 2 * 4));

    hipMemsetAsync(rowtok, 0xFF, (size_t)CAP * 4, stream);   // pad rows -> token -1
    hipMemsetAsync(ws + zstart, 0, zend - zstart, stream);   // weights/counters/stats

    k_transpose<<<dim3(DH / 64, DM / 64, NE), 256, 0, stream>>>(w1, w1T, DM, DH);  // -> [E][H][D]
    k_transpose<<<dim3(DM / 64, DH / 64, NE), 256, 0, stream>>>(w2, w2T, DH, DM);  // -> [E][D][H]
    k_router<<<NTOK / 4, 256, 0, stream>>>(x, rw, rb, xb, topidx, topw, probs8, zent);
    k_stats<<<NTOK / 256, 256, 0, stream>>>(topidx, probs8, zent, fcnt, sump, szent);
    k_scan<<<1, 1, 0, stream>>>(fcnt, offs);
    k_scatter<<<NTOK / 256, 256, 0, stream>>>(topidx, topw, offs, cnt2, rowtok, roww, slot);
    k_gemm1<<<16 * NRT, 256, 0, stream>>>(xb, w1T, b1, rowtok, offs, hid);
    k_gemm2<<<8 * NRT, 256, 0, stream>>>(hid, w2T, b2, roww, offs, outb);
    k_combine<<<NTOK, 256, 0, stream>>>(outb, slot, out);
    k_finalize<<<1, 1, 0, stream>>>(fcnt, sump, szent, out);
}